// Round 3
// baseline (436.637 us; speedup 1.0000x reference)
//
#include <hip/hip_runtime.h>
#include <hip/hip_bf16.h>

// WeightedLoss: two-pass Gram-matrix loss on MI355X.
// Round 3: 32x64 subtiled waves (half the live accumulator registers ->
// 3-4 waves/SIMD instead of 2) to fix the latency-bound/occupancy-capped
// regime seen in round 2 (MfmaUtil 7.3%, Occupancy 19.7%).
// ws layout:
//   [0]        Ob  bf16 8192x256  (4 MB)
//   [4194304]  Ln  bf16 8192x128  (2 MB)  (normalized labels)
//   [6291456]  sq  f32  8192
//   [6324224]  pos_sums f32 8192
//   [6356992]  neg_sums f32 8192
//   [6389760]  stats u32[3]: {smin_key, smax_key, d2max_key}

#define B_N 8192
#define NT   64      // 128-wide tiles per dim
#define TILE 128
#define NTRI (NT * (NT + 1) / 2)   // 2080 upper-tri tiles

typedef __attribute__((ext_vector_type(8))) short bf16x8;
typedef __attribute__((ext_vector_type(4))) float f32x4;

// order-preserving float<->uint for atomicMin/Max
__device__ __forceinline__ unsigned fenc(float f) {
    unsigned u = __float_as_uint(f);
    return (u & 0x80000000u) ? ~u : (u | 0x80000000u);
}
__device__ __forceinline__ float fdec(unsigned k) {
    unsigned u = (k & 0x80000000u) ? (k ^ 0x80000000u) : ~k;
    return __uint_as_float(u);
}

__device__ __forceinline__ void tri_decode(int idx, int& bi, int& bj) {
    int i = 0, rem = idx;
    while (rem >= NT - i) { rem -= NT - i; i++; }
    bi = i; bj = i + rem;
}

// ---------------------------------------------------------------- prep ----
__global__ __launch_bounds__(256) void prep_kernel(
    const float* __restrict__ outputs, const float* __restrict__ labels,
    __hip_bfloat16* __restrict__ Ob, __hip_bfloat16* __restrict__ Ln,
    float* __restrict__ sq, float* __restrict__ pos_sums,
    float* __restrict__ neg_sums, unsigned* __restrict__ stats) {
    int r = blockIdx.x, t = threadIdx.x;
    float v = outputs[(size_t)r * 256 + t];
    float s = v * v;
    #pragma unroll
    for (int m = 1; m < 64; m <<= 1) s += __shfl_xor(s, m);
    float lv = 0.f;
    if (t < 128) lv = labels[(size_t)r * 128 + t];
    float ls = lv * lv;
    #pragma unroll
    for (int m = 1; m < 64; m <<= 1) ls += __shfl_xor(ls, m);
    __shared__ float ws4[4];
    __shared__ float lsum2[2];
    if ((t & 63) == 0) ws4[t >> 6] = s;
    if (t < 128 && (t & 63) == 0) lsum2[t >> 6] = ls;
    __syncthreads();
    if (t == 0) sq[r] = ws4[0] + ws4[1] + ws4[2] + ws4[3];
    Ob[(size_t)r * 256 + t] = __float2bfloat16(v);
    if (t < 128) {
        float nrm = sqrtf(lsum2[0] + lsum2[1]) + 1e-12f;
        Ln[(size_t)r * 128 + t] = __float2bfloat16(lv / nrm);
    }
    if (t == 0) { pos_sums[r] = 0.f; neg_sums[r] = 0.f; }
    if (r == 0 && t == 0) {
        stats[0] = 0xFFFFFFFFu;  // smin key init
        stats[1] = 0u;           // smax key init
        stats[2] = 0u;           // d2max key init
    }
}

// ------------------------------------------- direct-global 32x64 gram ----
// Wave computes a 32x64 tile of X X^T via 16x16x32 bf16 MFMA, fragments
// loaded straight from row-major global (16 B contiguous per lane).
// Only 32 accumulator VGPRs live -> high occupancy, no LDS, no barriers.
template<int KDIM>
__device__ __forceinline__ void gram32x64(
    const __hip_bfloat16* __restrict__ X, int rowBase, int colBase,
    int l15, int quad, f32x4 (&acc)[2][4]) {
    const bf16x8* pa[2];
    const bf16x8* pb[4];
    #pragma unroll
    for (int mi = 0; mi < 2; mi++)
        pa[mi] = (const bf16x8*)(X + (size_t)(rowBase + mi * 16 + l15) * KDIM + quad * 8);
    #pragma unroll
    for (int ni = 0; ni < 4; ni++)
        pb[ni] = (const bf16x8*)(X + (size_t)(colBase + ni * 16 + l15) * KDIM + quad * 8);
    #pragma unroll
    for (int mi = 0; mi < 2; mi++)
        #pragma unroll
        for (int ni = 0; ni < 4; ni++) {
            f32x4 z = {0.f, 0.f, 0.f, 0.f};
            acc[mi][ni] = z;
        }
    #pragma unroll
    for (int k0 = 0; k0 < KDIM; k0 += 32) {
        bf16x8 a[2], b[4];
        #pragma unroll
        for (int mi = 0; mi < 2; mi++) a[mi] = pa[mi][k0 >> 3];
        #pragma unroll
        for (int ni = 0; ni < 4; ni++) b[ni] = pb[ni][k0 >> 3];
        #pragma unroll
        for (int mi = 0; mi < 2; mi++)
            #pragma unroll
            for (int ni = 0; ni < 4; ni++)
                acc[mi][ni] = __builtin_amdgcn_mfma_f32_16x16x32_bf16(
                    a[mi], b[ni], acc[mi][ni], 0, 0, 0);
    }
}

// ---------------------------------------------------------------- stats ----
// Upper-triangular tiles (symmetry): min/max of sim, max of d2.
// Subtiled: only one 32-reg accumulator live at a time.
__global__ __launch_bounds__(256, 4) void stats_kernel(
    const __hip_bfloat16* __restrict__ Ln, const __hip_bfloat16* __restrict__ Ob,
    const float* __restrict__ sq, unsigned* __restrict__ stats) {
    int bi, bj;
    tri_decode(blockIdx.x, bi, bj);
    int tid = threadIdx.x, lane = tid & 63, wid = tid >> 6;
    int wm = (wid >> 1) * 64, wn = (wid & 1) * 64;
    int l15 = lane & 15, quad = lane >> 4;
    int rowBase = bi * TILE + wm, colBase = bj * TILE + wn;

    float lmin = 1e30f, lmax = -1e30f, dmax = 0.f;
    f32x4 acc[2][4];

    #pragma unroll
    for (int h = 0; h < 2; h++) {
        gram32x64<128>(Ln, rowBase + h * 32, colBase, l15, quad, acc);
        #pragma unroll
        for (int mi = 0; mi < 2; mi++)
            #pragma unroll
            for (int ni = 0; ni < 4; ni++)
                #pragma unroll
                for (int r = 0; r < 4; r++) {
                    float s = acc[mi][ni][r];
                    lmin = fminf(lmin, s);
                    lmax = fmaxf(lmax, s);
                }
    }

    float sqj[4];
    #pragma unroll
    for (int ni = 0; ni < 4; ni++) sqj[ni] = sq[colBase + ni * 16 + l15];
    #pragma unroll
    for (int h = 0; h < 2; h++) {
        gram32x64<256>(Ob, rowBase + h * 32, colBase, l15, quad, acc);
        #pragma unroll
        for (int mi = 0; mi < 2; mi++) {
            f32x4 sqi = *(const f32x4*)&sq[rowBase + h * 32 + mi * 16 + quad * 4];
            #pragma unroll
            for (int r = 0; r < 4; r++)
                #pragma unroll
                for (int ni = 0; ni < 4; ni++) {
                    float d2 = fmaxf(sqi[r] + sqj[ni] - 2.f * acc[mi][ni][r], 0.f);
                    dmax = fmaxf(dmax, d2);
                }
        }
    }

    #pragma unroll
    for (int m = 1; m < 64; m <<= 1) {
        lmin = fminf(lmin, __shfl_xor(lmin, m));
        lmax = fmaxf(lmax, __shfl_xor(lmax, m));
        dmax = fmaxf(dmax, __shfl_xor(dmax, m));
    }
    __shared__ float red[3][4];
    if ((tid & 63) == 0) { red[0][wid] = lmin; red[1][wid] = lmax; red[2][wid] = dmax; }
    __syncthreads();
    if (tid == 0) {
        lmin = fminf(fminf(red[0][0], red[0][1]), fminf(red[0][2], red[0][3]));
        lmax = fmaxf(fmaxf(red[1][0], red[1][1]), fmaxf(red[1][2], red[1][3]));
        dmax = fmaxf(fmaxf(red[2][0], red[2][1]), fmaxf(red[2][2], red[2][3]));
        atomicMin(&stats[0], fenc(lmin));
        atomicMax(&stats[1], fenc(lmax));
        atomicMax(&stats[2], fenc(dmax));
    }
}

// ----------------------------------------------------------------- loss ----
// Upper-triangular grid; row-side sums (rows of bi) + column-side sums
// (rows of bj, symmetry). Subtiled 32x64: peak live acc = 64 regs.
__global__ __launch_bounds__(256, 3) void loss_kernel(
    const __hip_bfloat16* __restrict__ Ln, const __hip_bfloat16* __restrict__ Ob,
    const float* __restrict__ sq, const unsigned* __restrict__ stats,
    float* __restrict__ pos_sums, float* __restrict__ neg_sums) {
    int bi, bj;
    tri_decode(blockIdx.x, bi, bj);
    int tid = threadIdx.x, lane = tid & 63, wid = tid >> 6;
    int wm = (wid >> 1) * 64, wn = (wid & 1) * 64;
    int l15 = lane & 15, quad = lane >> 4;
    int rowBase = bi * TILE + wm, colBase = bj * TILE + wn;

    float smin = fdec(stats[0]);
    float smax = fdec(stats[1]);
    float d2max = fdec(stats[2]);
    float invr = 1.f / (smax - smin);
    float invem = rsqrtf(d2max);

    __shared__ float rP[TILE][2], rN[TILE][2];
    __shared__ float cP[TILE][2], cN[TILE][2];

    float sqj[4];
    #pragma unroll
    for (int ni = 0; ni < 4; ni++) sqj[ni] = sq[colBase + ni * 16 + l15];
    float cpsum[4] = {0.f, 0.f, 0.f, 0.f};
    float cnsum[4] = {0.f, 0.f, 0.f, 0.f};

    #pragma unroll
    for (int h = 0; h < 2; h++) {
        int rb = rowBase + h * 32;
        f32x4 accS[2][4], accG[2][4];
        gram32x64<128>(Ln, rb, colBase, l15, quad, accS);
        gram32x64<256>(Ob, rb, colBase, l15, quad, accG);

        #pragma unroll
        for (int mi = 0; mi < 2; mi++) {
            f32x4 sqi = *(const f32x4*)&sq[rb + mi * 16 + quad * 4];
            #pragma unroll
            for (int r = 0; r < 4; r++) {
                float psum = 0.f, nsum = 0.f;
                #pragma unroll
                for (int ni = 0; ni < 4; ni++) {
                    float s = accS[mi][ni][r];
                    float g = accG[mi][ni][r];
                    float sn = (s - smin) * invr;
                    float d2 = fmaxf(sqi[r] + sqj[ni] - 2.f * g, 0.f);
                    float eud = (d2 > 0.f) ? sqrtf(d2) * invem : 0.f;
                    float dist = eud + sn;
                    bool pos = sn > 0.5f;   // TAU
                    float pv = pos ? __expf(dist) : 0.f;
                    float nv = pos ? 0.f : __expf(1.0f - dist);   // MAG = 1
                    psum += pv;  nsum += nv;
                    cpsum[ni] += pv;  cnsum[ni] += nv;
                }
                #pragma unroll
                for (int m = 1; m < 16; m <<= 1) {
                    psum += __shfl_xor(psum, m);
                    nsum += __shfl_xor(nsum, m);
                }
                if (l15 == 0) {
                    int rr = wm + h * 32 + mi * 16 + quad * 4 + r;
                    rP[rr][wid & 1] = psum;
                    rN[rr][wid & 1] = nsum;
                }
            }
        }
    }
    // column-side: reduce over the 4 quads (lane bits 4,5)
    #pragma unroll
    for (int ni = 0; ni < 4; ni++) {
        #pragma unroll
        for (int m = 16; m < 64; m <<= 1) {
            cpsum[ni] += __shfl_xor(cpsum[ni], m);
            cnsum[ni] += __shfl_xor(cnsum[ni], m);
        }
        if (quad == 0) {
            int cc = wn + ni * 16 + l15;
            cP[cc][wid >> 1] = cpsum[ni];
            cN[cc][wid >> 1] = cnsum[ni];
        }
    }
    __syncthreads();
    if (tid < TILE) {
        atomicAdd(&pos_sums[bi * TILE + tid], rP[tid][0] + rP[tid][1]);
        atomicAdd(&neg_sums[bi * TILE + tid], rN[tid][0] + rN[tid][1]);
        if (bi != bj) {
            atomicAdd(&pos_sums[bj * TILE + tid], cP[tid][0] + cP[tid][1]);
            atomicAdd(&neg_sums[bj * TILE + tid], cN[tid][0] + cN[tid][1]);
        }
    }
}

// ------------------------------------------------------------- finalize ----
__global__ __launch_bounds__(256) void finalize_kernel(
    const float* __restrict__ pos_sums, const float* __restrict__ neg_sums,
    float* __restrict__ out) {
    int t = threadIdx.x;
    float acc = 0.f;
    for (int i = t; i < B_N; i += 256) {
        float p = pos_sums[i], n = neg_sums[i];
        float pl = fmaxf(logf(p), 0.f);
        float nl = (n > 0.f) ? fmaxf(logf(n), 0.f) : 0.f;
        acc += pl + nl;
    }
    #pragma unroll
    for (int m = 1; m < 64; m <<= 1) acc += __shfl_xor(acc, m);
    __shared__ float w4[4];
    if ((t & 63) == 0) w4[t >> 6] = acc;
    __syncthreads();
    if (t == 0) out[0] = (w4[0] + w4[1] + w4[2] + w4[3]) / (float)B_N;
}

// ------------------------------------------------------------------ entry ----
extern "C" void kernel_launch(void* const* d_in, const int* in_sizes, int n_in,
                              void* d_out, int out_size, void* d_ws, size_t ws_size,
                              hipStream_t stream) {
    const float* outputs = (const float*)d_in[0];
    const float* labels  = (const float*)d_in[1];
    float* out = (float*)d_out;
    char* ws = (char*)d_ws;
    __hip_bfloat16* Ob = (__hip_bfloat16*)(ws);
    __hip_bfloat16* Ln = (__hip_bfloat16*)(ws + 4194304);
    float* sq          = (float*)(ws + 6291456);
    float* pos_sums    = (float*)(ws + 6324224);
    float* neg_sums    = (float*)(ws + 6356992);
    unsigned* stats    = (unsigned*)(ws + 6389760);

    prep_kernel<<<B_N, 256, 0, stream>>>(outputs, labels, Ob, Ln, sq,
                                         pos_sums, neg_sums, stats);
    stats_kernel<<<NTRI, 256, 0, stream>>>(Ln, Ob, sq, stats);
    loss_kernel<<<NTRI, 256, 0, stream>>>(Ln, Ob, sq, stats,
                                          pos_sums, neg_sums);
    finalize_kernel<<<1, 256, 0, stream>>>(pos_sums, neg_sums, out);
}

// Round 4
// 400.891 us; speedup vs baseline: 1.0892x; 1.0892x over previous
//
#include <hip/hip_runtime.h>
#include <hip/hip_bf16.h>

// WeightedLoss: two-pass Gram-matrix loss on MI355X.
// Round 4: lean register structure (packed-f16 sn, single live accumulator),
// gentle __launch_bounds__(256,3) — round 3's (256,4) caused scratch spilling
// (WRITE_SIZE 275 MB on stats). Direct-from-global MFMA fragments, no LDS
// staging, upper-triangular grid with row+column accumulation.
// ws layout:
//   [0]        Ob  bf16 8192x256  (4 MB)
//   [4194304]  Ln  bf16 8192x128  (2 MB)  (normalized labels)
//   [6291456]  sq  f32  8192
//   [6324224]  pos_sums f32 8192
//   [6356992]  neg_sums f32 8192
//   [6389760]  stats u32[3]: {smin_key, smax_key, d2max_key}

#define B_N 8192
#define NT   64      // 128-wide tiles per dim
#define TILE 128
#define NTRI (NT * (NT + 1) / 2)   // 2080 upper-tri tiles

typedef __attribute__((ext_vector_type(8))) short bf16x8;
typedef __attribute__((ext_vector_type(4))) float f32x4;
typedef __attribute__((ext_vector_type(2))) _Float16 f16x2;

// order-preserving float<->uint for atomicMin/Max
__device__ __forceinline__ unsigned fenc(float f) {
    unsigned u = __float_as_uint(f);
    return (u & 0x80000000u) ? ~u : (u | 0x80000000u);
}
__device__ __forceinline__ float fdec(unsigned k) {
    unsigned u = (k & 0x80000000u) ? (k ^ 0x80000000u) : ~k;
    return __uint_as_float(u);
}

__device__ __forceinline__ void tri_decode(int idx, int& bi, int& bj) {
    int i = 0, rem = idx;
    while (rem >= NT - i) { rem -= NT - i; i++; }
    bi = i; bj = i + rem;
}

// ---------------------------------------------------------------- prep ----
__global__ __launch_bounds__(256) void prep_kernel(
    const float* __restrict__ outputs, const float* __restrict__ labels,
    __hip_bfloat16* __restrict__ Ob, __hip_bfloat16* __restrict__ Ln,
    float* __restrict__ sq, float* __restrict__ pos_sums,
    float* __restrict__ neg_sums, unsigned* __restrict__ stats) {
    int r = blockIdx.x, t = threadIdx.x;
    float v = outputs[(size_t)r * 256 + t];
    float s = v * v;
    #pragma unroll
    for (int m = 1; m < 64; m <<= 1) s += __shfl_xor(s, m);
    float lv = 0.f;
    if (t < 128) lv = labels[(size_t)r * 128 + t];
    float ls = lv * lv;
    #pragma unroll
    for (int m = 1; m < 64; m <<= 1) ls += __shfl_xor(ls, m);
    __shared__ float ws4[4];
    __shared__ float lsum2[2];
    if ((t & 63) == 0) ws4[t >> 6] = s;
    if (t < 128 && (t & 63) == 0) lsum2[t >> 6] = ls;
    __syncthreads();
    if (t == 0) sq[r] = ws4[0] + ws4[1] + ws4[2] + ws4[3];
    Ob[(size_t)r * 256 + t] = __float2bfloat16(v);
    if (t < 128) {
        float nrm = sqrtf(lsum2[0] + lsum2[1]) + 1e-12f;
        Ln[(size_t)r * 128 + t] = __float2bfloat16(lv / nrm);
    }
    if (t == 0) { pos_sums[r] = 0.f; neg_sums[r] = 0.f; }
    if (r == 0 && t == 0) {
        stats[0] = 0xFFFFFFFFu;  // smin key init
        stats[1] = 0u;           // smax key init
        stats[2] = 0u;           // d2max key init
    }
}

// ------------------------------------------- direct-global 32x64 gram ----
// Wave computes a 32x64 tile of X X^T via 16x16x32 bf16 MFMA, fragments
// loaded straight from row-major global (16 B contiguous per lane).
// Only 32 accumulator VGPRs live; no LDS, no barriers.
template<int KDIM>
__device__ __forceinline__ void gram32x64(
    const __hip_bfloat16* __restrict__ X, int rowBase, int colBase,
    int l15, int quad, f32x4 (&acc)[2][4]) {
    const bf16x8* pa[2];
    const bf16x8* pb[4];
    #pragma unroll
    for (int mi = 0; mi < 2; mi++)
        pa[mi] = (const bf16x8*)(X + (size_t)(rowBase + mi * 16 + l15) * KDIM + quad * 8);
    #pragma unroll
    for (int ni = 0; ni < 4; ni++)
        pb[ni] = (const bf16x8*)(X + (size_t)(colBase + ni * 16 + l15) * KDIM + quad * 8);
    #pragma unroll
    for (int mi = 0; mi < 2; mi++)
        #pragma unroll
        for (int ni = 0; ni < 4; ni++) {
            f32x4 z = {0.f, 0.f, 0.f, 0.f};
            acc[mi][ni] = z;
        }
    #pragma unroll
    for (int k0 = 0; k0 < KDIM; k0 += 32) {
        bf16x8 a[2], b[4];
        #pragma unroll
        for (int mi = 0; mi < 2; mi++) a[mi] = pa[mi][k0 >> 3];
        #pragma unroll
        for (int ni = 0; ni < 4; ni++) b[ni] = pb[ni][k0 >> 3];
        #pragma unroll
        for (int mi = 0; mi < 2; mi++)
            #pragma unroll
            for (int ni = 0; ni < 4; ni++)
                acc[mi][ni] = __builtin_amdgcn_mfma_f32_16x16x32_bf16(
                    a[mi], b[ni], acc[mi][ni], 0, 0, 0);
    }
}

// ---------------------------------------------------------------- stats ----
// Upper-triangular tiles (symmetry): min/max of sim, max of d2.
// One 32-reg accumulator live at a time; gentle bound (no spill).
__global__ __launch_bounds__(256, 3) void stats_kernel(
    const __hip_bfloat16* __restrict__ Ln, const __hip_bfloat16* __restrict__ Ob,
    const float* __restrict__ sq, unsigned* __restrict__ stats) {
    int bi, bj;
    tri_decode(blockIdx.x, bi, bj);
    int tid = threadIdx.x, lane = tid & 63, wid = tid >> 6;
    int wm = (wid >> 1) * 64, wn = (wid & 1) * 64;
    int l15 = lane & 15, quad = lane >> 4;
    int rowBase = bi * TILE + wm, colBase = bj * TILE + wn;

    float lmin = 1e30f, lmax = -1e30f, dmax = 0.f;
    f32x4 acc[2][4];

    #pragma unroll
    for (int h = 0; h < 2; h++) {
        gram32x64<128>(Ln, rowBase + h * 32, colBase, l15, quad, acc);
        #pragma unroll
        for (int mi = 0; mi < 2; mi++)
            #pragma unroll
            for (int ni = 0; ni < 4; ni++)
                #pragma unroll
                for (int r = 0; r < 4; r++) {
                    float s = acc[mi][ni][r];
                    lmin = fminf(lmin, s);
                    lmax = fmaxf(lmax, s);
                }
    }

    float sqj[4];
    #pragma unroll
    for (int ni = 0; ni < 4; ni++) sqj[ni] = sq[colBase + ni * 16 + l15];
    #pragma unroll
    for (int h = 0; h < 2; h++) {
        gram32x64<256>(Ob, rowBase + h * 32, colBase, l15, quad, acc);
        #pragma unroll
        for (int mi = 0; mi < 2; mi++) {
            f32x4 sqi = *(const f32x4*)&sq[rowBase + h * 32 + mi * 16 + quad * 4];
            #pragma unroll
            for (int r = 0; r < 4; r++)
                #pragma unroll
                for (int ni = 0; ni < 4; ni++) {
                    float d2 = fmaxf(sqi[r] + sqj[ni] - 2.f * acc[mi][ni][r], 0.f);
                    dmax = fmaxf(dmax, d2);
                }
        }
    }

    #pragma unroll
    for (int m = 1; m < 64; m <<= 1) {
        lmin = fminf(lmin, __shfl_xor(lmin, m));
        lmax = fmaxf(lmax, __shfl_xor(lmax, m));
        dmax = fmaxf(dmax, __shfl_xor(dmax, m));
    }
    __shared__ float red[3][4];
    if ((tid & 63) == 0) { red[0][wid] = lmin; red[1][wid] = lmax; red[2][wid] = dmax; }
    __syncthreads();
    if (tid == 0) {
        lmin = fminf(fminf(red[0][0], red[0][1]), fminf(red[0][2], red[0][3]));
        lmax = fmaxf(fmaxf(red[1][0], red[1][1]), fmaxf(red[1][2], red[1][3]));
        dmax = fmaxf(fmaxf(red[2][0], red[2][1]), fmaxf(red[2][2], red[2][3]));
        atomicMin(&stats[0], fenc(lmin));
        atomicMax(&stats[1], fenc(lmax));
        atomicMax(&stats[2], fenc(dmax));
    }
}

// ----------------------------------------------------------------- loss ----
// Upper-triangular grid; row-side sums (rows of bi) + column-side sums
// (rows of bj, symmetry). Per 32-row half: gram S -> normalize+pack sn to
// f16 pairs (16 regs) -> gram G reusing the SAME acc regs -> epilogue.
// Peak live acc = 32 regs; no spills at the (256,3) cap.
__global__ __launch_bounds__(256, 3) void loss_kernel(
    const __hip_bfloat16* __restrict__ Ln, const __hip_bfloat16* __restrict__ Ob,
    const float* __restrict__ sq, const unsigned* __restrict__ stats,
    float* __restrict__ pos_sums, float* __restrict__ neg_sums) {
    int bi, bj;
    tri_decode(blockIdx.x, bi, bj);
    int tid = threadIdx.x, lane = tid & 63, wid = tid >> 6;
    int wm = (wid >> 1) * 64, wn = (wid & 1) * 64;
    int l15 = lane & 15, quad = lane >> 4;
    int rowBase = bi * TILE + wm, colBase = bj * TILE + wn;

    float smin = fdec(stats[0]);
    float smax = fdec(stats[1]);
    float d2max = fdec(stats[2]);
    float invr = 1.f / (smax - smin);
    float invem = rsqrtf(d2max);

    __shared__ float rP[TILE][2], rN[TILE][2];
    __shared__ float cP[TILE][2], cN[TILE][2];

    float sqj[4];
    #pragma unroll
    for (int ni = 0; ni < 4; ni++) sqj[ni] = sq[colBase + ni * 16 + l15];
    float cpsum[4] = {0.f, 0.f, 0.f, 0.f};
    float cnsum[4] = {0.f, 0.f, 0.f, 0.f};

    #pragma unroll
    for (int h = 0; h < 2; h++) {
        int rb = rowBase + h * 32;
        f32x4 acc[2][4];

        // --- sim gram + normalize + pack to f16 (sn in [0,1], err ~5e-4) ---
        gram32x64<128>(Ln, rb, colBase, l15, quad, acc);
        f16x2 snp[2][4][2];
        #pragma unroll
        for (int mi = 0; mi < 2; mi++)
            #pragma unroll
            for (int ni = 0; ni < 4; ni++) {
                f16x2 lo, hi;
                lo[0] = (_Float16)((acc[mi][ni][0] - smin) * invr);
                lo[1] = (_Float16)((acc[mi][ni][1] - smin) * invr);
                hi[0] = (_Float16)((acc[mi][ni][2] - smin) * invr);
                hi[1] = (_Float16)((acc[mi][ni][3] - smin) * invr);
                snp[mi][ni][0] = lo;
                snp[mi][ni][1] = hi;
            }

        // --- outputs gram reusing the same acc registers ---
        gram32x64<256>(Ob, rb, colBase, l15, quad, acc);

        #pragma unroll
        for (int mi = 0; mi < 2; mi++) {
            f32x4 sqi = *(const f32x4*)&sq[rb + mi * 16 + quad * 4];
            #pragma unroll
            for (int r = 0; r < 4; r++) {
                float psum = 0.f, nsum = 0.f;
                #pragma unroll
                for (int ni = 0; ni < 4; ni++) {
                    float sn = (float)snp[mi][ni][r >> 1][r & 1];
                    float g  = acc[mi][ni][r];
                    float d2 = fmaxf(sqi[r] + sqj[ni] - 2.f * g, 0.f);
                    float eud = (d2 > 0.f) ? sqrtf(d2) * invem : 0.f;
                    float dist = eud + sn;
                    bool pos = sn > 0.5f;   // TAU
                    float pv = pos ? __expf(dist) : 0.f;
                    float nv = pos ? 0.f : __expf(1.0f - dist);   // MAG = 1
                    psum += pv;  nsum += nv;
                    cpsum[ni] += pv;  cnsum[ni] += nv;
                }
                #pragma unroll
                for (int m = 1; m < 16; m <<= 1) {
                    psum += __shfl_xor(psum, m);
                    nsum += __shfl_xor(nsum, m);
                }
                if (l15 == 0) {
                    int rr = wm + h * 32 + mi * 16 + quad * 4 + r;
                    rP[rr][wid & 1] = psum;
                    rN[rr][wid & 1] = nsum;
                }
            }
        }
    }
    // column-side: reduce over the 4 quads (lane bits 4,5)
    #pragma unroll
    for (int ni = 0; ni < 4; ni++) {
        #pragma unroll
        for (int m = 16; m < 64; m <<= 1) {
            cpsum[ni] += __shfl_xor(cpsum[ni], m);
            cnsum[ni] += __shfl_xor(cnsum[ni], m);
        }
        if (quad == 0) {
            int cc = wn + ni * 16 + l15;
            cP[cc][wid >> 1] = cpsum[ni];
            cN[cc][wid >> 1] = cnsum[ni];
        }
    }
    __syncthreads();
    if (tid < TILE) {
        atomicAdd(&pos_sums[bi * TILE + tid], rP[tid][0] + rP[tid][1]);
        atomicAdd(&neg_sums[bi * TILE + tid], rN[tid][0] + rN[tid][1]);
        if (bi != bj) {
            atomicAdd(&pos_sums[bj * TILE + tid], cP[tid][0] + cP[tid][1]);
            atomicAdd(&neg_sums[bj * TILE + tid], cN[tid][0] + cN[tid][1]);
        }
    }
}

// ------------------------------------------------------------- finalize ----
__global__ __launch_bounds__(256) void finalize_kernel(
    const float* __restrict__ pos_sums, const float* __restrict__ neg_sums,
    float* __restrict__ out) {
    int t = threadIdx.x;
    float acc = 0.f;
    for (int i = t; i < B_N; i += 256) {
        float p = pos_sums[i], n = neg_sums[i];
        float pl = fmaxf(logf(p), 0.f);
        float nl = (n > 0.f) ? fmaxf(logf(n), 0.f) : 0.f;
        acc += pl + nl;
    }
    #pragma unroll
    for (int m = 1; m < 64; m <<= 1) acc += __shfl_xor(acc, m);
    __shared__ float w4[4];
    if ((t & 63) == 0) w4[t >> 6] = acc;
    __syncthreads();
    if (t == 0) out[0] = (w4[0] + w4[1] + w4[2] + w4[3]) / (float)B_N;
}

// ------------------------------------------------------------------ entry ----
extern "C" void kernel_launch(void* const* d_in, const int* in_sizes, int n_in,
                              void* d_out, int out_size, void* d_ws, size_t ws_size,
                              hipStream_t stream) {
    const float* outputs = (const float*)d_in[0];
    const float* labels  = (const float*)d_in[1];
    float* out = (float*)d_out;
    char* ws = (char*)d_ws;
    __hip_bfloat16* Ob = (__hip_bfloat16*)(ws);
    __hip_bfloat16* Ln = (__hip_bfloat16*)(ws + 4194304);
    float* sq          = (float*)(ws + 6291456);
    float* pos_sums    = (float*)(ws + 6324224);
    float* neg_sums    = (float*)(ws + 6356992);
    unsigned* stats    = (unsigned*)(ws + 6389760);

    prep_kernel<<<B_N, 256, 0, stream>>>(outputs, labels, Ob, Ln, sq,
                                         pos_sums, neg_sums, stats);
    stats_kernel<<<NTRI, 256, 0, stream>>>(Ln, Ob, sq, stats);
    loss_kernel<<<NTRI, 256, 0, stream>>>(Ln, Ob, sq, stats,
                                          pos_sums, neg_sums);
    finalize_kernel<<<1, 256, 0, stream>>>(pos_sums, neg_sums, out);
}

// Round 5
// 268.034 us; speedup vs baseline: 1.6290x; 1.4957x over previous
//
#include <hip/hip_runtime.h>
#include <hip/hip_bf16.h>

// WeightedLoss round 5: materialize fp16 sim/eud tiles in pass A (stats),
// stream them in pass B (loss). Kills the duplicated latency-bound gram
// recomputation (rounds 2-4: every reg-squeeze attempt spilled; only the
// plain 64x64/wave acc[4][4] structure is spill-free). XCD swizzle for L2.
// ws layout:
//   [0]          Ob  bf16 8192x256  (4 MB)
//   [4194304]    Ln  bf16 8192x128  (2 MB)
//   [6291456]    sq  f32 8192
//   [6324224]    pos_sums f32 8192
//   [6356992]    neg_sums f32 8192
//   [6389760]    stats u32[3]
//   [6389824]    simT fp16, tri-packed 2080 tiles x 16384   (68.2 MB)
//   [74547264]   eudT fp16, same layout                     (68.2 MB)
// total needed: 142,704,704 B. Fallback (recompute loss) if ws smaller.

#define B_N 8192
#define NT   64
#define TILE 128
#define NTRI 2080
#define WS_NEEDED 142704704ull

typedef __attribute__((ext_vector_type(8))) short bf16x8;
typedef __attribute__((ext_vector_type(4))) float f32x4;
typedef __attribute__((ext_vector_type(2))) _Float16 f16x2;

__device__ __forceinline__ unsigned fenc(float f) {
    unsigned u = __float_as_uint(f);
    return (u & 0x80000000u) ? ~u : (u | 0x80000000u);
}
__device__ __forceinline__ float fdec(unsigned k) {
    unsigned u = (k & 0x80000000u) ? (k ^ 0x80000000u) : ~k;
    return __uint_as_float(u);
}
__device__ __forceinline__ unsigned pack2(float a, float b) {
    f16x2 p; p[0] = (_Float16)a; p[1] = (_Float16)b;
    return *(unsigned*)&p;
}

// XCD-swizzled upper-tri decode: blocks congruent mod 8 (same XCD) get a
// contiguous tri range -> compact bi band per XCD -> A-rows stay in L2.
__device__ __forceinline__ int tri_decode_swz(int b, int& bi, int& bj) {
    int t = (b & 7) * (NTRI / 8) + (b >> 3);
    int i = 0, rem = t;
    while (rem >= NT - i) { rem -= NT - i; i++; }
    bi = i; bj = i + rem;
    return t;
}

// ---------------------------------------------------------------- prep ----
// 4 rows/block, one wave per row; float4/float2 vector loads.
__global__ __launch_bounds__(256) void prep_kernel(
    const float* __restrict__ outputs, const float* __restrict__ labels,
    __hip_bfloat16* __restrict__ Ob, __hip_bfloat16* __restrict__ Ln,
    float* __restrict__ sq, float* __restrict__ pos_sums,
    float* __restrict__ neg_sums, unsigned* __restrict__ stats) {
    int w = threadIdx.x >> 6, lane = threadIdx.x & 63;
    int r = blockIdx.x * 4 + w;
    f32x4 v = ((const f32x4*)outputs)[r * 64 + lane];
    float s = v[0]*v[0] + v[1]*v[1] + v[2]*v[2] + v[3]*v[3];
    #pragma unroll
    for (int m = 1; m < 64; m <<= 1) s += __shfl_xor(s, m);
    if (lane == 0) { sq[r] = s; pos_sums[r] = 0.f; neg_sums[r] = 0.f; }
    __hip_bfloat16 o4[4];
    #pragma unroll
    for (int i = 0; i < 4; i++) o4[i] = __float2bfloat16(v[i]);
    *(uint2*)&Ob[(size_t)r * 256 + lane * 4] = *(uint2*)o4;

    float2 lv = ((const float2*)labels)[r * 64 + lane];
    float ls = lv.x * lv.x + lv.y * lv.y;
    #pragma unroll
    for (int m = 1; m < 64; m <<= 1) ls += __shfl_xor(ls, m);
    float nrm = sqrtf(ls) + 1e-12f;
    __hip_bfloat16 l2[2] = { __float2bfloat16(lv.x / nrm),
                             __float2bfloat16(lv.y / nrm) };
    *(unsigned*)&Ln[(size_t)r * 128 + lane * 2] = *(unsigned*)l2;

    if (blockIdx.x == 0 && threadIdx.x == 0) {
        stats[0] = 0xFFFFFFFFu; stats[1] = 0u; stats[2] = 0u;
    }
}

// ------------------------------------------- direct-global 64x64 gram ----
template<int KDIM>
__device__ __forceinline__ void gram64(
    const __hip_bfloat16* __restrict__ X, int rowBase, int colBase,
    int l15, int quad, f32x4 (&acc)[4][4]) {
    const bf16x8* pa[4];
    const bf16x8* pb[4];
    #pragma unroll
    for (int mi = 0; mi < 4; mi++)
        pa[mi] = (const bf16x8*)(X + (size_t)(rowBase + mi * 16 + l15) * KDIM + quad * 8);
    #pragma unroll
    for (int ni = 0; ni < 4; ni++)
        pb[ni] = (const bf16x8*)(X + (size_t)(colBase + ni * 16 + l15) * KDIM + quad * 8);
    #pragma unroll
    for (int mi = 0; mi < 4; mi++)
        #pragma unroll
        for (int ni = 0; ni < 4; ni++) {
            f32x4 z = {0.f, 0.f, 0.f, 0.f};
            acc[mi][ni] = z;
        }
    #pragma unroll
    for (int k0 = 0; k0 < KDIM; k0 += 32) {
        bf16x8 a[4], b[4];
        #pragma unroll
        for (int mi = 0; mi < 4; mi++) a[mi] = pa[mi][k0 >> 3];
        #pragma unroll
        for (int ni = 0; ni < 4; ni++) b[ni] = pb[ni][k0 >> 3];
        #pragma unroll
        for (int mi = 0; mi < 4; mi++)
            #pragma unroll
            for (int ni = 0; ni < 4; ni++)
                acc[mi][ni] = __builtin_amdgcn_mfma_f32_16x16x32_bf16(
                    a[mi], b[ni], acc[mi][ni], 0, 0, 0);
    }
}

// ---------------------------------------------------------------- stats ----
// One gram live at a time (spill-free round-2 structure). Tracks min/max of
// sim and max of d2; optionally materializes fp16 sim_raw and eud_raw tiles
// in slot-major layout: u32 index = t*8192 + pp*256 + tid, pp=(mi*4+ni)*2+h,
// packing rows r=2h,2h+1 (coalesced 1 KB per wave-store).
__global__ __launch_bounds__(256, 2) void stats_kernel(
    const __hip_bfloat16* __restrict__ Ln, const __hip_bfloat16* __restrict__ Ob,
    const float* __restrict__ sq, unsigned* __restrict__ stats,
    unsigned* __restrict__ simT, unsigned* __restrict__ eudT, int store) {
    int bi, bj;
    int t = tri_decode_swz(blockIdx.x, bi, bj);
    int tid = threadIdx.x, lane = tid & 63, wid = tid >> 6;
    int wm = (wid >> 1) * 64, wn = (wid & 1) * 64;
    int l15 = lane & 15, quad = lane >> 4;
    int rowBase = bi * TILE + wm, colBase = bj * TILE + wn;
    size_t tb = (size_t)t * 8192 + tid;

    float lmin = 1e30f, lmax = -1e30f, dmax = 0.f;
    f32x4 acc[4][4];

    gram64<128>(Ln, rowBase, colBase, l15, quad, acc);
    #pragma unroll
    for (int mi = 0; mi < 4; mi++)
        #pragma unroll
        for (int ni = 0; ni < 4; ni++)
            #pragma unroll
            for (int h = 0; h < 2; h++) {
                float s0 = acc[mi][ni][2 * h], s1 = acc[mi][ni][2 * h + 1];
                lmin = fminf(lmin, fminf(s0, s1));
                lmax = fmaxf(lmax, fmaxf(s0, s1));
                if (store) simT[tb + (size_t)((mi * 4 + ni) * 2 + h) * 256] = pack2(s0, s1);
            }

    gram64<256>(Ob, rowBase, colBase, l15, quad, acc);
    float sqj[4];
    #pragma unroll
    for (int ni = 0; ni < 4; ni++) sqj[ni] = sq[colBase + ni * 16 + l15];
    #pragma unroll
    for (int mi = 0; mi < 4; mi++) {
        f32x4 sqi = *(const f32x4*)&sq[rowBase + mi * 16 + quad * 4];
        #pragma unroll
        for (int ni = 0; ni < 4; ni++)
            #pragma unroll
            for (int h = 0; h < 2; h++) {
                float d20 = fmaxf(sqi[2*h]   + sqj[ni] - 2.f * acc[mi][ni][2*h],   0.f);
                float d21 = fmaxf(sqi[2*h+1] + sqj[ni] - 2.f * acc[mi][ni][2*h+1], 0.f);
                dmax = fmaxf(dmax, fmaxf(d20, d21));
                if (store) {
                    float e0 = (d20 > 0.f) ? sqrtf(d20) : 0.f;
                    float e1 = (d21 > 0.f) ? sqrtf(d21) : 0.f;
                    eudT[tb + (size_t)((mi * 4 + ni) * 2 + h) * 256] = pack2(e0, e1);
                }
            }
    }

    #pragma unroll
    for (int m = 1; m < 64; m <<= 1) {
        lmin = fminf(lmin, __shfl_xor(lmin, m));
        lmax = fmaxf(lmax, __shfl_xor(lmax, m));
        dmax = fmaxf(dmax, __shfl_xor(dmax, m));
    }
    __shared__ float red[3][4];
    if ((tid & 63) == 0) { red[0][wid] = lmin; red[1][wid] = lmax; red[2][wid] = dmax; }
    __syncthreads();
    if (tid == 0) {
        lmin = fminf(fminf(red[0][0], red[0][1]), fminf(red[0][2], red[0][3]));
        lmax = fmaxf(fmaxf(red[1][0], red[1][1]), fmaxf(red[1][2], red[1][3]));
        dmax = fmaxf(fmaxf(red[2][0], red[2][1]), fmaxf(red[2][2], red[2][3]));
        atomicMin(&stats[0], fenc(lmin));
        atomicMax(&stats[1], fenc(lmax));
        atomicMax(&stats[2], fenc(dmax));
    }
}

// ----------------------------------------------------------- loss stream ----
// Pure streaming: read fp16 sim/eud tiles, exp epilogue, row+col sums.
__global__ __launch_bounds__(256) void loss_stream_kernel(
    const unsigned* __restrict__ simT, const unsigned* __restrict__ eudT,
    const unsigned* __restrict__ stats,
    float* __restrict__ pos_sums, float* __restrict__ neg_sums) {
    int bi, bj;
    int t = tri_decode_swz(blockIdx.x, bi, bj);
    int tid = threadIdx.x, lane = tid & 63, wid = tid >> 6;
    int wm = (wid >> 1) * 64, wn = (wid & 1) * 64;
    int l15 = lane & 15, quad = lane >> 4;
    size_t tb = (size_t)t * 8192 + tid;

    float smin = fdec(stats[0]);
    float smax = fdec(stats[1]);
    float d2max = fdec(stats[2]);
    float invr = 1.f / (smax - smin);
    float invem = rsqrtf(d2max);

    __shared__ float rP[TILE][2], rN[TILE][2];
    __shared__ float cP[TILE][2], cN[TILE][2];
    float cpsum[4] = {0.f, 0.f, 0.f, 0.f};
    float cnsum[4] = {0.f, 0.f, 0.f, 0.f};

    #pragma unroll
    for (int mi = 0; mi < 4; mi++) {
        #pragma unroll
        for (int h = 0; h < 2; h++) {
            float ps0 = 0.f, ps1 = 0.f, ns0 = 0.f, ns1 = 0.f;
            #pragma unroll
            for (int ni = 0; ni < 4; ni++) {
                size_t off = tb + (size_t)((mi * 4 + ni) * 2 + h) * 256;
                unsigned sv = simT[off];
                unsigned ev = eudT[off];
                f16x2 sp = *(f16x2*)&sv;
                f16x2 ep = *(f16x2*)&ev;
                #pragma unroll
                for (int e = 0; e < 2; e++) {
                    float sn = ((float)sp[e] - smin) * invr;
                    float dist = (float)ep[e] * invem + sn;
                    bool pos = sn > 0.5f;   // TAU
                    float pv = pos ? __expf(dist) : 0.f;
                    float nv = pos ? 0.f : __expf(1.0f - dist);  // MAG = 1
                    if (e == 0) { ps0 += pv; ns0 += nv; }
                    else        { ps1 += pv; ns1 += nv; }
                    cpsum[ni] += pv;  cnsum[ni] += nv;
                }
            }
            #pragma unroll
            for (int m = 1; m < 16; m <<= 1) {
                ps0 += __shfl_xor(ps0, m);  ns0 += __shfl_xor(ns0, m);
                ps1 += __shfl_xor(ps1, m);  ns1 += __shfl_xor(ns1, m);
            }
            if (l15 == 0) {
                int rr = wm + mi * 16 + quad * 4 + 2 * h;
                rP[rr][wid & 1] = ps0;  rN[rr][wid & 1] = ns0;
                rP[rr + 1][wid & 1] = ps1;  rN[rr + 1][wid & 1] = ns1;
            }
        }
    }
    #pragma unroll
    for (int ni = 0; ni < 4; ni++) {
        #pragma unroll
        for (int m = 16; m < 64; m <<= 1) {
            cpsum[ni] += __shfl_xor(cpsum[ni], m);
            cnsum[ni] += __shfl_xor(cnsum[ni], m);
        }
        if (quad == 0) {
            int cc = wn + ni * 16 + l15;
            cP[cc][wid >> 1] = cpsum[ni];
            cN[cc][wid >> 1] = cnsum[ni];
        }
    }
    __syncthreads();
    if (tid < TILE) {
        atomicAdd(&pos_sums[bi * TILE + tid], rP[tid][0] + rP[tid][1]);
        atomicAdd(&neg_sums[bi * TILE + tid], rN[tid][0] + rN[tid][1]);
        if (bi != bj) {
            atomicAdd(&pos_sums[bj * TILE + tid], cP[tid][0] + cP[tid][1]);
            atomicAdd(&neg_sums[bj * TILE + tid], cN[tid][0] + cN[tid][1]);
        }
    }
}

// ------------------------------------------------ loss fallback (recompute) ----
__global__ __launch_bounds__(256, 2) void loss_recompute_kernel(
    const __hip_bfloat16* __restrict__ Ln, const __hip_bfloat16* __restrict__ Ob,
    const float* __restrict__ sq, const unsigned* __restrict__ stats,
    float* __restrict__ pos_sums, float* __restrict__ neg_sums) {
    int bi, bj;
    tri_decode_swz(blockIdx.x, bi, bj);
    int tid = threadIdx.x, lane = tid & 63, wid = tid >> 6;
    int wm = (wid >> 1) * 64, wn = (wid & 1) * 64;
    int l15 = lane & 15, quad = lane >> 4;
    int rowBase = bi * TILE + wm, colBase = bj * TILE + wn;

    f32x4 accS[4][4], accG[4][4];
    gram64<128>(Ln, rowBase, colBase, l15, quad, accS);
    gram64<256>(Ob, rowBase, colBase, l15, quad, accG);

    float smin = fdec(stats[0]);
    float smax = fdec(stats[1]);
    float d2max = fdec(stats[2]);
    float invr = 1.f / (smax - smin);
    float invem = rsqrtf(d2max);

    __shared__ float rP[TILE][2], rN[TILE][2];
    __shared__ float cP[TILE][2], cN[TILE][2];
    float sqj[4];
    #pragma unroll
    for (int ni = 0; ni < 4; ni++) sqj[ni] = sq[colBase + ni * 16 + l15];
    float cpsum[4] = {0.f, 0.f, 0.f, 0.f};
    float cnsum[4] = {0.f, 0.f, 0.f, 0.f};

    #pragma unroll
    for (int mi = 0; mi < 4; mi++) {
        f32x4 sqi = *(const f32x4*)&sq[rowBase + mi * 16 + quad * 4];
        #pragma unroll
        for (int r = 0; r < 4; r++) {
            float psum = 0.f, nsum = 0.f;
            #pragma unroll
            for (int ni = 0; ni < 4; ni++) {
                float sn = (accS[mi][ni][r] - smin) * invr;
                float d2 = fmaxf(sqi[r] + sqj[ni] - 2.f * accG[mi][ni][r], 0.f);
                float eud = (d2 > 0.f) ? sqrtf(d2) * invem : 0.f;
                float dist = eud + sn;
                bool pos = sn > 0.5f;
                float pv = pos ? __expf(dist) : 0.f;
                float nv = pos ? 0.f : __expf(1.0f - dist);
                psum += pv;  nsum += nv;
                cpsum[ni] += pv;  cnsum[ni] += nv;
            }
            #pragma unroll
            for (int m = 1; m < 16; m <<= 1) {
                psum += __shfl_xor(psum, m);
                nsum += __shfl_xor(nsum, m);
            }
            if (l15 == 0) {
                int rr = wm + mi * 16 + quad * 4 + r;
                rP[rr][wid & 1] = psum;
                rN[rr][wid & 1] = nsum;
            }
        }
    }
    #pragma unroll
    for (int ni = 0; ni < 4; ni++) {
        #pragma unroll
        for (int m = 16; m < 64; m <<= 1) {
            cpsum[ni] += __shfl_xor(cpsum[ni], m);
            cnsum[ni] += __shfl_xor(cnsum[ni], m);
        }
        if (quad == 0) {
            int cc = wn + ni * 16 + l15;
            cP[cc][wid >> 1] = cpsum[ni];
            cN[cc][wid >> 1] = cnsum[ni];
        }
    }
    __syncthreads();
    if (tid < TILE) {
        atomicAdd(&pos_sums[bi * TILE + tid], rP[tid][0] + rP[tid][1]);
        atomicAdd(&neg_sums[bi * TILE + tid], rN[tid][0] + rN[tid][1]);
        if (bi != bj) {
            atomicAdd(&pos_sums[bj * TILE + tid], cP[tid][0] + cP[tid][1]);
            atomicAdd(&neg_sums[bj * TILE + tid], cN[tid][0] + cN[tid][1]);
        }
    }
}

// ------------------------------------------------------------- finalize ----
__global__ __launch_bounds__(256) void finalize_kernel(
    const float* __restrict__ pos_sums, const float* __restrict__ neg_sums,
    float* __restrict__ out) {
    int t = threadIdx.x;
    float acc = 0.f;
    for (int i = t; i < B_N; i += 256) {
        float p = pos_sums[i], n = neg_sums[i];
        float pl = fmaxf(logf(p), 0.f);
        float nl = (n > 0.f) ? fmaxf(logf(n), 0.f) : 0.f;
        acc += pl + nl;
    }
    #pragma unroll
    for (int m = 1; m < 64; m <<= 1) acc += __shfl_xor(acc, m);
    __shared__ float w4[4];
    if ((t & 63) == 0) w4[t >> 6] = acc;
    __syncthreads();
    if (t == 0) out[0] = (w4[0] + w4[1] + w4[2] + w4[3]) / (float)B_N;
}

// ------------------------------------------------------------------ entry ----
extern "C" void kernel_launch(void* const* d_in, const int* in_sizes, int n_in,
                              void* d_out, int out_size, void* d_ws, size_t ws_size,
                              hipStream_t stream) {
    const float* outputs = (const float*)d_in[0];
    const float* labels  = (const float*)d_in[1];
    float* out = (float*)d_out;
    char* ws = (char*)d_ws;
    __hip_bfloat16* Ob = (__hip_bfloat16*)(ws);
    __hip_bfloat16* Ln = (__hip_bfloat16*)(ws + 4194304);
    float* sq          = (float*)(ws + 6291456);
    float* pos_sums    = (float*)(ws + 6324224);
    float* neg_sums    = (float*)(ws + 6356992);
    unsigned* stats    = (unsigned*)(ws + 6389760);
    unsigned* simT     = (unsigned*)(ws + 6389824);
    unsigned* eudT     = (unsigned*)(ws + 74547264);
    int big = (ws_size >= WS_NEEDED) ? 1 : 0;

    prep_kernel<<<B_N / 4, 256, 0, stream>>>(outputs, labels, Ob, Ln, sq,
                                             pos_sums, neg_sums, stats);
    stats_kernel<<<NTRI, 256, 0, stream>>>(Ln, Ob, sq, stats, simT, eudT, big);
    if (big)
        loss_stream_kernel<<<NTRI, 256, 0, stream>>>(simT, eudT, stats,
                                                     pos_sums, neg_sums);
    else
        loss_recompute_kernel<<<NTRI, 256, 0, stream>>>(Ln, Ob, sq, stats,
                                                        pos_sums, neg_sums);
    finalize_kernel<<<1, 256, 0, stream>>>(pos_sums, neg_sums, out);
}